// Round 1
// baseline (282.800 us; speedup 1.0000x reference)
//
#include <hip/hip_runtime.h>
#include <math.h>

#define B 256
#define N 1152
#define C_ 10
#define OUT 16
#define IN 8
#define KO 160          // C_*OUT
#define MB 16           // batch tile for s-partial
#define NC 64           // n-chunk for s-partial
#define NCH 18          // N / NC
#define XS_STRIDE (NC*IN + 8)   // pad to break 4-way LDS bank conflict

// ---------------- s-partial: partial[ch][b][k*16+o] = sum_{n in chunk} c[n,k] * (W[n,k,o,:] . x[b,n,:])
__global__ __launch_bounds__(256) void k_s_partial(
    const float* __restrict__ x, const float* __restrict__ W,
    const float* __restrict__ c, float* __restrict__ partial)
{
    __shared__ float xs[MB][XS_STRIDE];   // 16 x 520 floats = 33.3 KB
    __shared__ float cs[NC][C_];          // 2.56 KB

    const int tid = threadIdx.x;
    const int bt  = blockIdx.x;   // 0..15
    const int ch  = blockIdx.y;   // 0..17
    const int b0  = bt * MB;
    const int n0  = ch * NC;

    // load x tile: xs[bl][nl*8+i] = x[b0+bl][n0+nl][i]  (row = 512 contiguous floats = 128 float4)
    for (int idx = tid; idx < MB * NC * IN / 4; idx += 256) {
        int bl = idx >> 7;          // /128
        int r  = idx & 127;
        float4 val = *(const float4*)(x + (size_t)(b0 + bl) * (N * IN) + (size_t)n0 * IN + r * 4);
        *(float4*)(&xs[bl][r * 4]) = val;
    }
    if (c) {
        for (int idx = tid; idx < NC * C_; idx += 256) {
            int nl = idx / C_, k = idx % C_;
            cs[nl][k] = c[(size_t)(n0 + nl) * C_ + k];
        }
    }
    __syncthreads();

    const int o  = tid & 15;
    const int bl = tid >> 4;

    float acc[C_];
#pragma unroll
    for (int k = 0; k < C_; ++k) acc[k] = 0.f;

    for (int nl = 0; nl < NC; ++nl) {
        float xv[IN];
#pragma unroll
        for (int i = 0; i < IN; ++i) xv[i] = xs[bl][nl * IN + i];
        const float* Wn = W + (size_t)(n0 + nl) * (KO * IN) + o * IN;
#pragma unroll
        for (int k = 0; k < C_; ++k) {
            const float4* wp = (const float4*)(Wn + k * (OUT * IN));
            float4 w0 = wp[0], w1 = wp[1];
            float d = w0.x * xv[0] + w0.y * xv[1] + w0.z * xv[2] + w0.w * xv[3]
                    + w1.x * xv[4] + w1.y * xv[5] + w1.z * xv[6] + w1.w * xv[7];
            float cw = c ? cs[nl][k] : 0.1f;   // it0: softmax(0) = 1/C exactly
            acc[k] += cw * d;
        }
    }

    float* pp = partial + (size_t)ch * (B * KO) + (size_t)(b0 + bl) * KO + o;
#pragma unroll
    for (int k = 0; k < C_; ++k) pp[k * OUT] = acc[k];
}

// ---------------- reduce partials over chunks + squash; v always, out on last iter
__global__ __launch_bounds__(256) void k_reduce_squash(
    const float* __restrict__ partial, float* __restrict__ v, float* __restrict__ out)
{
    int idx = blockIdx.x * 256 + threadIdx.x;  // 0..40959
    float s = 0.f;
#pragma unroll
    for (int ch = 0; ch < NCH; ++ch) s += partial[(size_t)ch * (B * KO) + idx];
    float vv = s * fabsf(s) / (1.f + s * s);
    v[idx] = vv;
    if (out) out[idx] = vv;
}

// ---------------- a-pass: b_ij[n][k] (+)= (1/B) sum_{b,o} (W[n,k,o,:].x[b,n,:]) * v[b,k,o]
__global__ __launch_bounds__(256) void k_a(
    const float* __restrict__ x, const float* __restrict__ W,
    const float* __restrict__ v, float* __restrict__ bij, int accumulate)
{
    const int n = blockIdx.x;
    const int tid = threadIdx.x;

    __shared__ float Wl[KO][IN + 1];   // padded: stride 9 -> conflict-free
    __shared__ float xsl[B][IN];       // 8 KB
    __shared__ float red[256][C_];     // 10 KB

    for (int idx = tid; idx < KO * IN; idx += 256)
        Wl[idx >> 3][idx & 7] = W[(size_t)n * (KO * IN) + idx];
    for (int idx = tid; idx < B * IN / 4; idx += 256) {   // 512 float4
        int bb = idx >> 1, r = idx & 1;
        *(float4*)(&xsl[bb][r * 4]) = *(const float4*)(x + (size_t)bb * (N * IN) + (size_t)n * IN + r * 4);
    }
    __syncthreads();

    const int o = tid & 15;
    const int blane = tid >> 4;

    float part[C_];
#pragma unroll
    for (int k = 0; k < C_; ++k) part[k] = 0.f;

    for (int t = 0; t < B / 16; ++t) {
        int bb = blane + t * 16;
        float xv[IN];
#pragma unroll
        for (int i = 0; i < IN; ++i) xv[i] = xsl[bb][i];
        const float* vb = v + (size_t)bb * KO + o;
#pragma unroll
        for (int k = 0; k < C_; ++k) {
            const float* wp = &Wl[k * OUT + o][0];
            float d = 0.f;
#pragma unroll
            for (int i = 0; i < IN; ++i) d += wp[i] * xv[i];
            part[k] += d * vb[k * OUT];
        }
    }

#pragma unroll
    for (int k = 0; k < C_; ++k) red[tid][k] = part[k];
    __syncthreads();
    for (int off = 128; off > 0; off >>= 1) {
        if (tid < off) {
#pragma unroll
            for (int k = 0; k < C_; ++k) red[tid][k] += red[tid + off][k];
        }
        __syncthreads();
    }
    if (tid < C_) {
        float a = red[0][tid] * (1.0f / B);
        float* bp = bij + (size_t)n * C_ + tid;
        *bp = accumulate ? (*bp + a) : a;
    }
}

// ---------------- softmax over k (10) per n
__global__ __launch_bounds__(256) void k_softmax(
    const float* __restrict__ bij, float* __restrict__ c)
{
    int n = blockIdx.x * 256 + threadIdx.x;
    if (n >= N) return;
    float b[C_], m = -1e30f;
#pragma unroll
    for (int k = 0; k < C_; ++k) { b[k] = bij[(size_t)n * C_ + k]; m = fmaxf(m, b[k]); }
    float s = 0.f;
#pragma unroll
    for (int k = 0; k < C_; ++k) { float e = __expf(b[k] - m); b[k] = e; s += e; }
    float inv = 1.f / s;
#pragma unroll
    for (int k = 0; k < C_; ++k) c[(size_t)n * C_ + k] = b[k] * inv;
}

extern "C" void kernel_launch(void* const* d_in, const int* in_sizes, int n_in,
                              void* d_out, int out_size, void* d_ws, size_t ws_size,
                              hipStream_t stream)
{
    const float* x = (const float*)d_in[0];   // [B, N, IN]
    const float* W = (const float*)d_in[1];   // [1, N, C, OUT, IN]
    float* out = (float*)d_out;               // [B, C, OUT, 1] = 40960 floats
    float* ws  = (float*)d_ws;

    float* bij  = ws;                 // 11520
    float* c    = ws + 11520;         // 11520
    float* v    = ws + 23040;         // 40960
    float* part = ws + 64000;         // 18 * 40960 = 737280  (total ~3.2 MB)

    dim3 gS(16, NCH);

    // iteration 0: c = 1/C exactly (softmax of zeros); b_ij = a  (write mode, no init needed)
    k_s_partial<<<gS, 256, 0, stream>>>(x, W, nullptr, part);
    k_reduce_squash<<<160, 256, 0, stream>>>(part, v, nullptr);
    k_a<<<N, 256, 0, stream>>>(x, W, v, bij, 0);

    // iteration 1
    k_softmax<<<5, 256, 0, stream>>>(bij, c);
    k_s_partial<<<gS, 256, 0, stream>>>(x, W, c, part);
    k_reduce_squash<<<160, 256, 0, stream>>>(part, v, nullptr);
    k_a<<<N, 256, 0, stream>>>(x, W, v, bij, 1);

    // iteration 2 (final: write d_out)
    k_softmax<<<5, 256, 0, stream>>>(bij, c);
    k_s_partial<<<gS, 256, 0, stream>>>(x, W, c, part);
    k_reduce_squash<<<160, 256, 0, stream>>>(part, v, out);
}

// Round 2
// 207.503 us; speedup vs baseline: 1.3629x; 1.3629x over previous
//
#include <hip/hip_runtime.h>
#include <math.h>

#define B 256
#define N 1152
#define C_ 10
#define OUT 16
#define IN 8
#define KO 160          // C_*OUT
#define MB 16           // batch tile for s-partial
#define NC 32           // n-chunk for s-partial
#define NCH 36          // N / NC
#define KG 5            // capsules per k-group (2 groups)
#define XS_STRIDE (NC*IN + 8)   // 264: rows land 8 banks apart -> conflict-free

// ---------------- s-partial: partial[ch][b][k*16+o] = sum_{n in chunk} c[n,k] * (W[n,k,o,:] . x[b,n,:])
// grid (16, 36, 2): batch-tile, n-chunk, k-group
__global__ __launch_bounds__(256, 4) void k_s_partial(
    const float* __restrict__ x, const float* __restrict__ W,
    const float* __restrict__ c, float* __restrict__ partial)
{
    __shared__ float xs[MB][XS_STRIDE];   // 16 x 264 floats = 16.9 KB
    __shared__ float cs[NC][KG];          // 640 B

    const int tid = threadIdx.x;
    const int bt  = blockIdx.x;   // 0..15
    const int ch  = blockIdx.y;   // 0..35
    const int kg  = blockIdx.z;   // 0..1
    const int b0  = bt * MB;
    const int n0  = ch * NC;
    const int k0  = kg * KG;

    // load x tile: row = 256 contiguous floats = 64 float4
    for (int idx = tid; idx < MB * NC * IN / 4; idx += 256) {
        int bl = idx >> 6;
        int r  = idx & 63;
        float4 val = *(const float4*)(x + (size_t)(b0 + bl) * (N * IN) + (size_t)n0 * IN + r * 4);
        *(float4*)(&xs[bl][r * 4]) = val;
    }
    if (c) {
        for (int idx = tid; idx < NC * KG; idx += 256) {
            int nl = idx / KG, kk = idx % KG;
            cs[nl][kk] = c[(size_t)(n0 + nl) * C_ + (k0 + kk)];
        }
    }
    __syncthreads();

    const int o  = tid & 15;
    const int bl = tid >> 4;

    float acc[KG];
#pragma unroll
    for (int kk = 0; kk < KG; ++kk) acc[kk] = 0.f;

    const float* Wbase = W + (size_t)n0 * (KO * IN) + (size_t)(k0 * OUT + o) * IN;

#pragma unroll 2
    for (int nl = 0; nl < NC; ++nl) {
        float xv[IN];
#pragma unroll
        for (int i = 0; i < IN; ++i) xv[i] = xs[bl][nl * IN + i];
        const float* Wn = Wbase + (size_t)nl * (KO * IN);
#pragma unroll
        for (int kk = 0; kk < KG; ++kk) {
            const float4* wp = (const float4*)(Wn + kk * (OUT * IN));
            float4 w0 = wp[0], w1 = wp[1];
            float d = w0.x * xv[0] + w0.y * xv[1] + w0.z * xv[2] + w0.w * xv[3]
                    + w1.x * xv[4] + w1.y * xv[5] + w1.z * xv[6] + w1.w * xv[7];
            float cw = c ? cs[nl][kk] : 0.1f;   // it0: softmax(0) = 1/C exactly
            acc[kk] += cw * d;
        }
    }

    float* pp = partial + (size_t)ch * (B * KO) + (size_t)(b0 + bl) * KO + (size_t)k0 * OUT + o;
#pragma unroll
    for (int kk = 0; kk < KG; ++kk) pp[kk * OUT] = acc[kk];
}

// ---------------- reduce partials over chunks + squash; v always, out on last iter
__global__ __launch_bounds__(256) void k_reduce_squash(
    const float* __restrict__ partial, float* __restrict__ v, float* __restrict__ out)
{
    int idx = blockIdx.x * 256 + threadIdx.x;  // 0..40959
    float s = 0.f;
#pragma unroll
    for (int ch = 0; ch < NCH; ++ch) s += partial[(size_t)ch * (B * KO) + idx];
    float vv = s * fabsf(s) / (1.f + s * s);
    v[idx] = vv;
    if (out) out[idx] = vv;
}

// ---------------- a-pass: b_ij[n][k] (+)= (1/B) sum_{b,o} (W[n,k,o,:].x[b,n,:]) * v[b,k,o]
__global__ __launch_bounds__(256) void k_a(
    const float* __restrict__ x, const float* __restrict__ W,
    const float* __restrict__ v, float* __restrict__ bij, int accumulate)
{
    const int n = blockIdx.x;
    const int tid = threadIdx.x;

    __shared__ float Wl[KO][IN + 1];   // padded: stride 9 -> conflict-free
    __shared__ float xsl[B][IN];       // 8 KB
    __shared__ float red[256][C_];     // 10 KB

    for (int idx = tid; idx < KO * IN; idx += 256)
        Wl[idx >> 3][idx & 7] = W[(size_t)n * (KO * IN) + idx];
    for (int idx = tid; idx < B * IN / 4; idx += 256) {   // 512 float4
        int bb = idx >> 1, r = idx & 1;
        *(float4*)(&xsl[bb][r * 4]) = *(const float4*)(x + (size_t)bb * (N * IN) + (size_t)n * IN + r * 4);
    }
    __syncthreads();

    const int o = tid & 15;
    const int blane = tid >> 4;

    float part[C_];
#pragma unroll
    for (int k = 0; k < C_; ++k) part[k] = 0.f;

    for (int t = 0; t < B / 16; ++t) {
        int bb = blane + t * 16;
        float xv[IN];
#pragma unroll
        for (int i = 0; i < IN; ++i) xv[i] = xsl[bb][i];
        const float* vb = v + (size_t)bb * KO + o;
#pragma unroll
        for (int k = 0; k < C_; ++k) {
            const float* wp = &Wl[k * OUT + o][0];
            float d = 0.f;
#pragma unroll
            for (int i = 0; i < IN; ++i) d += wp[i] * xv[i];
            part[k] += d * vb[k * OUT];
        }
    }

#pragma unroll
    for (int k = 0; k < C_; ++k) red[tid][k] = part[k];
    __syncthreads();
    for (int off = 128; off > 0; off >>= 1) {
        if (tid < off) {
#pragma unroll
            for (int k = 0; k < C_; ++k) red[tid][k] += red[tid + off][k];
        }
        __syncthreads();
    }
    if (tid < C_) {
        float a = red[0][tid] * (1.0f / B);
        float* bp = bij + (size_t)n * C_ + tid;
        *bp = accumulate ? (*bp + a) : a;
    }
}

// ---------------- softmax over k (10) per n
__global__ __launch_bounds__(256) void k_softmax(
    const float* __restrict__ bij, float* __restrict__ c)
{
    int n = blockIdx.x * 256 + threadIdx.x;
    if (n >= N) return;
    float b[C_], m = -1e30f;
#pragma unroll
    for (int k = 0; k < C_; ++k) { b[k] = bij[(size_t)n * C_ + k]; m = fmaxf(m, b[k]); }
    float s = 0.f;
#pragma unroll
    for (int k = 0; k < C_; ++k) { float e = __expf(b[k] - m); b[k] = e; s += e; }
    float inv = 1.f / s;
#pragma unroll
    for (int k = 0; k < C_; ++k) c[(size_t)n * C_ + k] = b[k] * inv;
}

extern "C" void kernel_launch(void* const* d_in, const int* in_sizes, int n_in,
                              void* d_out, int out_size, void* d_ws, size_t ws_size,
                              hipStream_t stream)
{
    const float* x = (const float*)d_in[0];   // [B, N, IN]
    const float* W = (const float*)d_in[1];   // [1, N, C, OUT, IN]
    float* out = (float*)d_out;               // [B, C, OUT, 1] = 40960 floats
    float* ws  = (float*)d_ws;

    float* part = ws;                         // 36 * 40960 = 1474560 floats (5.9 MB)
    float* bij  = ws + 1474560;               // 11520
    float* c    = bij + 11520;                // 11520
    float* v    = c + 11520;                  // 40960

    dim3 gS(16, NCH, 2);

    // iteration 0: c = 1/C exactly (softmax of zeros); b_ij = a  (write mode, no init needed)
    k_s_partial<<<gS, 256, 0, stream>>>(x, W, nullptr, part);
    k_reduce_squash<<<160, 256, 0, stream>>>(part, v, nullptr);
    k_a<<<N, 256, 0, stream>>>(x, W, v, bij, 0);

    // iteration 1
    k_softmax<<<5, 256, 0, stream>>>(bij, c);
    k_s_partial<<<gS, 256, 0, stream>>>(x, W, c, part);
    k_reduce_squash<<<160, 256, 0, stream>>>(part, v, nullptr);
    k_a<<<N, 256, 0, stream>>>(x, W, v, bij, 1);

    // iteration 2 (final: write d_out)
    k_softmax<<<5, 256, 0, stream>>>(bij, c);
    k_s_partial<<<gS, 256, 0, stream>>>(x, W, c, part);
    k_reduce_squash<<<160, 256, 0, stream>>>(part, v, out);
}